// Round 5
// baseline (278.745 us; speedup 1.0000x reference)
//
#include <hip/hip_runtime.h>
#include <hip/hip_bf16.h>

typedef _Float16 half8 __attribute__((ext_vector_type(8)));
typedef _Float16 half4 __attribute__((ext_vector_type(4)));
typedef _Float16 half2t __attribute__((ext_vector_type(2)));
typedef float floatx4 __attribute__((ext_vector_type(4)));
typedef float floatx16 __attribute__((ext_vector_type(16)));
typedef unsigned int uint2v __attribute__((ext_vector_type(2)));

#define LOG2E 1.44269504088896340736f

__device__ __forceinline__ half8 cvt8r(floatx4 a, floatx4 b) {
    half8 h;
    h[0] = (_Float16)a[0]; h[1] = (_Float16)a[1]; h[2] = (_Float16)a[2]; h[3] = (_Float16)a[3];
    h[4] = (_Float16)b[0]; h[5] = (_Float16)b[1]; h[6] = (_Float16)b[2]; h[7] = (_Float16)b[3];
    return h;
}

union H8U { half8 h; half2t v2[4]; uint2v u[2]; };

__device__ __forceinline__ half2t pk16(float a, float b) {
    return __builtin_bit_cast(half2t, __builtin_amdgcn_cvt_pkrtz(a, b));
}

// ---------------- K1: transpose + convert W (f32 [512x512]) -> WT fp16 [n][k] ----------------
__global__ __launch_bounds__(256) void transpose_w_kernel(
        const float* __restrict__ Wq, const float* __restrict__ Wk,
        const float* __restrict__ Wv, const float* __restrict__ Wo,
        _Float16* __restrict__ out) {
    const float* W = (blockIdx.z == 0) ? Wq : (blockIdx.z == 1) ? Wk : (blockIdx.z == 2) ? Wv : Wo;
    _Float16* o = out + (size_t)blockIdx.z * 512 * 512;
    __shared__ __align__(16) _Float16 t[64][72];
    int r0 = blockIdx.x * 64, c0 = blockIdx.y * 64;
    int tid = threadIdx.x;
    for (int i = 0; i < 2; i++) {
        int f = i * 256 + tid;
        int row = f >> 3, seg = f & 7;
        const float* p = W + (size_t)(r0 + row) * 512 + c0 + seg * 8;
        *(half8*)&t[row][seg * 8] = cvt8r(*(const floatx4*)p, *(const floatx4*)(p + 4));
    }
    __syncthreads();
    for (int i = 0; i < 2; i++) {
        int f = i * 256 + tid;
        int crow = f >> 3, seg = f & 7;
        half8 hv;
        for (int j = 0; j < 8; j++) hv[j] = t[seg * 8 + j][crow];
        *(half8*)(o + (size_t)(c0 + crow) * 512 + r0 + seg * 8) = hv;
    }
}

// ---------------- K2: QKV projection GEMM, 64x128 tiles; dead K/V blocks skipped ----------------
__global__ __launch_bounds__(256) void gemm_qkv_kernel(
        const float* __restrict__ Xq, const float* __restrict__ Xk, const float* __restrict__ Xv,
        const _Float16* __restrict__ WTall,
        const float* __restrict__ bq, const float* __restrict__ bk, const float* __restrict__ bv,
        const int* __restrict__ vlens,
        _Float16* __restrict__ qo, _Float16* __restrict__ ko2, _Float16* __restrict__ vto) {
    int z = blockIdx.z;
    int mBase = blockIdx.x * 64, nBase = blockIdx.y * 128;

    if (z >= 1) {
        int b_ = mBase >> 11, s0 = mBase & 2047;
        int L = vlens[b_];
        if (s0 >= L && !(z == 2 && L == 0)) return;
    }

    const float* X = (z == 0) ? Xq : (z == 1) ? Xk : Xv;
    const _Float16* BT = WTall + (size_t)z * 512 * 512;
    const float* bias = (z == 0) ? bq : (z == 1) ? bk : bv;

    __shared__ __align__(16) _Float16 Asm[64][72];
    __shared__ __align__(16) _Float16 Bsm[128][72];

    int tid = threadIdx.x;
    int wave = tid >> 6, lane = tid & 63;
    int lrow = lane & 15, quad = lane >> 4;
    int mrow = wave * 16 + lrow;

    const floatx4 fz = {0.f, 0.f, 0.f, 0.f};
    floatx4 acc[8];
    for (int i = 0; i < 8; i++) acc[i] = fz;

    int arow[2], aseg[2], brow[4], bseg[4];
    for (int i = 0; i < 2; i++) { int f = i * 256 + tid; arow[i] = f >> 3; aseg[i] = f & 7; }
    for (int i = 0; i < 4; i++) { int f = i * 256 + tid; brow[i] = f >> 3; bseg[i] = f & 7; }

    floatx4 areg[2][2];
    half8 breg[4];
    for (int i = 0; i < 2; i++) {
        const float* pa = X + (size_t)(mBase + arow[i]) * 512 + aseg[i] * 8;
        areg[i][0] = *(const floatx4*)pa;
        areg[i][1] = *(const floatx4*)(pa + 4);
    }
    for (int i = 0; i < 4; i++)
        breg[i] = *(const half8*)(BT + (size_t)(nBase + brow[i]) * 512 + bseg[i] * 8);

    for (int kb = 0; kb < 512; kb += 64) {
        for (int i = 0; i < 2; i++) *(half8*)&Asm[arow[i]][aseg[i] * 8] = cvt8r(areg[i][0], areg[i][1]);
        for (int i = 0; i < 4; i++) *(half8*)&Bsm[brow[i]][bseg[i] * 8] = breg[i];
        __syncthreads();
        if (kb + 64 < 512) {
            int kn = kb + 64;
            for (int i = 0; i < 2; i++) {
                const float* pa = X + (size_t)(mBase + arow[i]) * 512 + kn + aseg[i] * 8;
                areg[i][0] = *(const floatx4*)pa;
                areg[i][1] = *(const floatx4*)(pa + 4);
            }
            for (int i = 0; i < 4; i++)
                breg[i] = *(const half8*)(BT + (size_t)(nBase + brow[i]) * 512 + kn + bseg[i] * 8);
        }
        for (int kc = 0; kc < 2; kc++) {
            int ko_ = kc * 32 + quad * 8;
            half8 a = *(const half8*)&Asm[mrow][ko_];
            for (int nt = 0; nt < 8; nt++) {
                half8 b = *(const half8*)&Bsm[nt * 16 + lrow][ko_];
                acc[nt] = __builtin_amdgcn_mfma_f32_16x16x32_f16(a, b, acc[nt], 0, 0, 0);
            }
        }
        __syncthreads();
    }

    if (z == 2) {
        for (int nt = 0; nt < 8; nt++) {
            int gc = nBase + nt * 16 + lrow;
            float bb = bias[gc];
            int h = gc >> 6, hd = gc & 63;
            int gr = mBase + wave * 16 + quad * 4;
            int b_ = gr >> 11, s = gr & 2047;
            half4 hv;
            for (int r = 0; r < 4; r++) hv[r] = (_Float16)(acc[nt][r] + bb);
            *(half4*)(vto + (((size_t)(b_ * 8 + h) * 64 + hd) * 2048 + s)) = hv;
        }
    } else {
        _Float16* out = (z == 0) ? qo : ko2;
        for (int nt = 0; nt < 8; nt++) {
            int gc = nBase + nt * 16 + lrow;
            float bb = bias[gc];
            int h = gc >> 6, hd = gc & 63;
            for (int r = 0; r < 4; r++) {
                int gr = mBase + wave * 16 + quad * 4 + r;
                int b_ = gr >> 11, s = gr & 2047;
                out[(((size_t)b_ * 8 + h) * 2048 + s) * 64 + hd] = (_Float16)(acc[nt][r] + bb);
            }
        }
    }
}

// ---------------- K3: flash attention v14: LDS-free, barrier-free, 1 wave/block ----------------
// K/V are L2/L3-resident (512 KB per head). Each wave owns 32 q-rows, streams K/V fragments
// DIRECTLY from global (verified identical mapping to the old swizzled-LDS reads):
//   QK A-frag:  K[key = kt*64+t*32+l31][kc*16 + hi*8 ..+7]            (16B load)
//   PV B-frag:  V^T[hd = (half*32)+l31][kt*64 + s*16 + 4*hi (+8)]     (8B pair)
// No __syncthreads anywhere -> no barrier drain; 24 independent loads in flight per tile.
// Block mapping: idx&7 = head (XCD-local via round-robin dispatch), j&3 = batch -> each XCD
// works 4 bh (2 MB K/V, L2-fits) and every XCD gets identical total work (sum_b L_b).
__global__ __launch_bounds__(64) void attn_kernel(
        const _Float16* __restrict__ qws, const _Float16* __restrict__ kws,
        const _Float16* __restrict__ vtws, const int* __restrict__ vlens,
        _Float16* __restrict__ aout) {
    int idx = blockIdx.x;
    int h = idx & 7;
    int j = idx >> 3;
    int b = j & 3;
    int q0 = (j >> 2) * 32;
    int bh = b * 8 + h;
    int L = vlens[b];
    bool uni = (L == 0);
    int nkt = uni ? 32 : ((L + 63) >> 6);
    int nfull = uni ? 0 : (L >> 6);

    int lane = threadIdx.x;
    int l31 = lane & 31, hi = lane >> 5;

    const _Float16* kb = kws + (size_t)bh * 2048 * 64;
    const _Float16* vb = vtws + (size_t)bh * 64 * 2048;
    const _Float16* vrow0 = vb + (size_t)l31 * 2048;
    const _Float16* vrow1 = vb + (size_t)(32 + l31) * 2048;
    const _Float16* krow = kb + (size_t)l31 * 64 + hi * 8;

    // Q B-fragments: lane holds Q[q0+l31][kc*16 + hi*8 + j]; softmax scale folded in
    half8 qf[4];
    {
        const _Float16* qrow = qws + ((size_t)bh * 2048 + q0 + l31) * 64;
#pragma unroll
        for (int kc = 0; kc < 4; kc++) {
            qf[kc] = *(const half8*)(qrow + kc * 16 + hi * 8);
            qf[kc] = qf[kc] * (_Float16)(0.125f * LOG2E);
        }
    }

    floatx16 oc0, oc1;
#pragma unroll
    for (int i = 0; i < 16; i++) { oc0[i] = 0.f; oc1[i] = 0.f; }
    float rs = 0.f;

    for (int kt = 0; kt < nkt; kt++) {
        int kk = kt * 64;
        int ng = uni ? 2 : ((L - kk >= 33) ? 2 : 1);   // valid 32-key groups this tile

        // ---- issue ALL tile loads (independent; compiler waits per-use) ----
        half8 kf[2][4];
        H8U vf[2][2][2];   // [t][s2][output-half]
#pragma unroll
        for (int t = 0; t < 2; t++) {
#pragma unroll
            for (int kc = 0; kc < 4; kc++)
                kf[t][kc] = *(const half8*)(krow + (size_t)(kk + t * 32) * 64 + kc * 16);
#pragma unroll
            for (int s2 = 0; s2 < 2; s2++) {
                int col = kk + (t * 2 + s2) * 16 + 4 * hi;
                vf[t][s2][0].u[0] = *(const uint2v*)(vrow0 + col);
                vf[t][s2][0].u[1] = *(const uint2v*)(vrow0 + col + 8);
                vf[t][s2][1].u[0] = *(const uint2v*)(vrow1 + col);
                vf[t][s2][1].u[1] = *(const uint2v*)(vrow1 + col + 8);
            }
        }

#pragma unroll
        for (int t = 0; t < 2; t++) {
            if (t >= ng) break;

            // S^T = K*(Q*c)^T : col = q (l31), row r -> key kk + t*32 + (r&3)+8*(r>>2)+4*hi
            floatx16 sacc;
#pragma unroll
            for (int i = 0; i < 16; i++) sacc[i] = 0.f;
#pragma unroll
            for (int kc = 0; kc < 4; kc++)
                sacc = __builtin_amdgcn_mfma_f32_32x32x16_f16(kf[t][kc], qf[kc], sacc, 0, 0, 0);

            float p[16];
            if (kt < nfull) {
#pragma unroll
                for (int r = 0; r < 16; r++) p[r] = exp2f(sacc[r]);
            } else {
                int kb0 = kk + t * 32 + 4 * hi;
#pragma unroll
                for (int r = 0; r < 16; r++) {
                    int key = kb0 + (r & 3) + 8 * (r >> 2);
                    p[r] = uni ? 1.0f : ((key < L) ? exp2f(sacc[r]) : 0.0f);
                }
            }
            rs += (((p[0] + p[1]) + (p[2] + p[3])) + ((p[4] + p[5]) + (p[6] + p[7])))
                + (((p[8] + p[9]) + (p[10] + p[11])) + ((p[12] + p[13]) + (p[14] + p[15])));

            // PV: k-slot sigma(hi,j) = 16s + 4hi + (j&3) + 8*(j>>2); A = lane-local p
#pragma unroll
            for (int s2 = 0; s2 < 2; s2++) {
                H8U pa;
#pragma unroll
                for (int jj = 0; jj < 4; jj++)
                    pa.v2[jj] = pk16(p[s2 * 8 + jj * 2], p[s2 * 8 + jj * 2 + 1]);
                oc0 = __builtin_amdgcn_mfma_f32_32x32x16_f16(pa.h, vf[t][s2][0].h, oc0, 0, 0, 0);
                oc1 = __builtin_amdgcn_mfma_f32_32x32x16_f16(pa.h, vf[t][s2][1].h, oc1, 0, 0, 0);
            }
        }
    }

    // rowsum[q=l31] = own half + other half; normalize and store
    float rstot = rs + __shfl_xor(rs, 32, 64);
    float myinv = 1.0f / rstot;
    _Float16* outb = aout + ((size_t)b * 2048 + q0) * 512 + h * 64;
#pragma unroll
    for (int r = 0; r < 16; r++) {
        int qi = (r & 3) + 8 * (r >> 2) + 4 * hi;
        float w = __shfl(myinv, qi, 64);
        outb[(size_t)qi * 512 + l31] = (_Float16)(oc0[r] * w);
        outb[(size_t)qi * 512 + 32 + l31] = (_Float16)(oc1[r] * w);
    }
}

// ---------------- K4: output projection, 64x128 tiles (reg-prefetch dbuf) -> f32 ----------------
__global__ __launch_bounds__(256) void gemm_out_kernel(
        const _Float16* __restrict__ A, const _Float16* __restrict__ BT,
        const float* __restrict__ bias, float* __restrict__ out) {
    __shared__ __align__(16) _Float16 Asm[64][72];
    __shared__ __align__(16) _Float16 Bsm[128][72];

    int tid = threadIdx.x;
    int wave = tid >> 6, lane = tid & 63;
    int lrow = lane & 15, quad = lane >> 4;
    int mBase = blockIdx.x * 64, nBase = blockIdx.y * 128;
    int mrow = wave * 16 + lrow;

    const floatx4 fz = {0.f, 0.f, 0.f, 0.f};
    floatx4 acc[8];
    for (int i = 0; i < 8; i++) acc[i] = fz;

    int arow[2], aseg[2], brow[4], bseg[4];
    for (int i = 0; i < 2; i++) { int f = i * 256 + tid; arow[i] = f >> 3; aseg[i] = f & 7; }
    for (int i = 0; i < 4; i++) { int f = i * 256 + tid; brow[i] = f >> 3; bseg[i] = f & 7; }

    half8 areg[2], breg[4];
    for (int i = 0; i < 2; i++)
        areg[i] = *(const half8*)(A + (size_t)(mBase + arow[i]) * 512 + aseg[i] * 8);
    for (int i = 0; i < 4; i++)
        breg[i] = *(const half8*)(BT + (size_t)(nBase + brow[i]) * 512 + bseg[i] * 8);

    for (int kb = 0; kb < 512; kb += 64) {
        for (int i = 0; i < 2; i++) *(half8*)&Asm[arow[i]][aseg[i] * 8] = areg[i];
        for (int i = 0; i < 4; i++) *(half8*)&Bsm[brow[i]][bseg[i] * 8] = breg[i];
        __syncthreads();
        if (kb + 64 < 512) {
            int kn = kb + 64;
            for (int i = 0; i < 2; i++)
                areg[i] = *(const half8*)(A + (size_t)(mBase + arow[i]) * 512 + kn + aseg[i] * 8);
            for (int i = 0; i < 4; i++)
                breg[i] = *(const half8*)(BT + (size_t)(nBase + brow[i]) * 512 + kn + bseg[i] * 8);
        }
        for (int kc = 0; kc < 2; kc++) {
            int ko_ = kc * 32 + quad * 8;
            half8 a = *(const half8*)&Asm[mrow][ko_];
            for (int nt = 0; nt < 8; nt++) {
                half8 b = *(const half8*)&Bsm[nt * 16 + lrow][ko_];
                acc[nt] = __builtin_amdgcn_mfma_f32_16x16x32_f16(a, b, acc[nt], 0, 0, 0);
            }
        }
        __syncthreads();
    }

    for (int nt = 0; nt < 8; nt++) {
        int gc = nBase + nt * 16 + lrow;
        float bb = bias[gc];
        for (int r = 0; r < 4; r++) {
            int gr = mBase + wave * 16 + quad * 4 + r;
            out[(size_t)gr * 512 + gc] = acc[nt][r] + bb;
        }
    }
}

extern "C" void kernel_launch(void* const* d_in, const int* in_sizes, int n_in,
                              void* d_out, int out_size, void* d_ws, size_t ws_size,
                              hipStream_t stream) {
    const float* Q  = (const float*)d_in[0];
    const float* K  = (const float*)d_in[1];
    const float* V  = (const float*)d_in[2];
    const int*   VL = (const int*)d_in[3];
    const float* Wq = (const float*)d_in[4];
    const float* bq = (const float*)d_in[5];
    const float* Wk = (const float*)d_in[6];
    const float* bk = (const float*)d_in[7];
    const float* Wv = (const float*)d_in[8];
    const float* bv = (const float*)d_in[9];
    const float* Wo = (const float*)d_in[10];
    const float* bo = (const float*)d_in[11];

    char* ws = (char*)d_ws;
    _Float16* WT   = (_Float16*)ws;                                  // 2 MiB
    _Float16* qws  = (_Float16*)(ws + (size_t)(2)  * 1024 * 1024);   // 8 MiB [bh][s][hd]
    _Float16* kws  = (_Float16*)(ws + (size_t)(10) * 1024 * 1024);   // 8 MiB [bh][s][hd]
    _Float16* aout = (_Float16*)(ws + (size_t)(18) * 1024 * 1024);   // 8 MiB [8192,512]
    _Float16* vtws = (_Float16*)(ws + (size_t)(26) * 1024 * 1024);   // 8 MiB [bh][hd][s]

    transpose_w_kernel<<<dim3(8, 8, 4), 256, 0, stream>>>(Wq, Wk, Wv, Wo, WT);
    gemm_qkv_kernel<<<dim3(128, 4, 3), 256, 0, stream>>>(Q, K, V, WT, bq, bk, bv, VL, qws, kws, vtws);
    attn_kernel<<<dim3(2048, 1, 1), 64, 0, stream>>>(qws, kws, vtws, VL, aout);
    gemm_out_kernel<<<dim3(128, 4, 1), 256, 0, stream>>>(aout, WT + (size_t)3 * 512 * 512, bo, (float*)d_out);
}

// Round 6
// 198.640 us; speedup vs baseline: 1.4033x; 1.4033x over previous
//
#include <hip/hip_runtime.h>
#include <hip/hip_bf16.h>

typedef _Float16 half8 __attribute__((ext_vector_type(8)));
typedef _Float16 half4 __attribute__((ext_vector_type(4)));
typedef _Float16 half2t __attribute__((ext_vector_type(2)));
typedef float floatx4 __attribute__((ext_vector_type(4)));
typedef float floatx16 __attribute__((ext_vector_type(16)));
typedef unsigned int uint2v __attribute__((ext_vector_type(2)));

#define LOG2E 1.44269504088896340736f

__device__ __forceinline__ half8 cvt8r(floatx4 a, floatx4 b) {
    half8 h;
    h[0] = (_Float16)a[0]; h[1] = (_Float16)a[1]; h[2] = (_Float16)a[2]; h[3] = (_Float16)a[3];
    h[4] = (_Float16)b[0]; h[5] = (_Float16)b[1]; h[6] = (_Float16)b[2]; h[7] = (_Float16)b[3];
    return h;
}

union H8U { half8 h; half2t v2[4]; uint2v u[2]; };

// ---------------- K1: transpose + convert W (f32 [512x512]) -> WT fp16 [n][k] ----------------
__global__ __launch_bounds__(256) void transpose_w_kernel(
        const float* __restrict__ Wq, const float* __restrict__ Wk,
        const float* __restrict__ Wv, const float* __restrict__ Wo,
        _Float16* __restrict__ out) {
    const float* W = (blockIdx.z == 0) ? Wq : (blockIdx.z == 1) ? Wk : (blockIdx.z == 2) ? Wv : Wo;
    _Float16* o = out + (size_t)blockIdx.z * 512 * 512;
    __shared__ __align__(16) _Float16 t[64][72];
    int r0 = blockIdx.x * 64, c0 = blockIdx.y * 64;
    int tid = threadIdx.x;
    for (int i = 0; i < 2; i++) {
        int f = i * 256 + tid;
        int row = f >> 3, seg = f & 7;
        const float* p = W + (size_t)(r0 + row) * 512 + c0 + seg * 8;
        *(half8*)&t[row][seg * 8] = cvt8r(*(const floatx4*)p, *(const floatx4*)(p + 4));
    }
    __syncthreads();
    for (int i = 0; i < 2; i++) {
        int f = i * 256 + tid;
        int crow = f >> 3, seg = f & 7;
        half8 hv;
        for (int j = 0; j < 8; j++) hv[j] = t[seg * 8 + j][crow];
        *(half8*)(o + (size_t)(c0 + crow) * 512 + r0 + seg * 8) = hv;
    }
}

// ---------------- K2: QKV projection GEMM, 128x128 tiles (2 m-strips/wave) ----------------
__global__ __launch_bounds__(256) void gemm_qkv_kernel(
        const float* __restrict__ Xq, const float* __restrict__ Xk, const float* __restrict__ Xv,
        const _Float16* __restrict__ WTall,
        const float* __restrict__ bq, const float* __restrict__ bk, const float* __restrict__ bv,
        const int* __restrict__ vlens,
        _Float16* __restrict__ qo, _Float16* __restrict__ ko2, _Float16* __restrict__ vto) {
    int z = blockIdx.z;
    int mBase = blockIdx.x * 128, nBase = blockIdx.y * 128;

    if (z >= 1) {
        int b_ = mBase >> 11, s0 = mBase & 2047;
        int L = vlens[b_];
        if (s0 >= L && !(z == 2 && L == 0)) return;
    }

    const float* X = (z == 0) ? Xq : (z == 1) ? Xk : Xv;
    const _Float16* BT = WTall + (size_t)z * 512 * 512;
    const float* bias = (z == 0) ? bq : (z == 1) ? bk : bv;

    __shared__ __align__(16) _Float16 Asm[128][72];
    __shared__ __align__(16) _Float16 Bsm[128][72];

    int tid = threadIdx.x;
    int wave = tid >> 6, lane = tid & 63;
    int lrow = lane & 15, quad = lane >> 4;
    int mrow = wave * 16 + lrow;

    const floatx4 fz = {0.f, 0.f, 0.f, 0.f};
    floatx4 acc[2][8];
    for (int mh = 0; mh < 2; mh++)
        for (int i = 0; i < 8; i++) acc[mh][i] = fz;

    int row4[4], seg4[4];
    for (int i = 0; i < 4; i++) { int f = i * 256 + tid; row4[i] = f >> 3; seg4[i] = f & 7; }

    floatx4 areg[4][2];
    half8 breg[4];
    for (int i = 0; i < 4; i++) {
        const float* pa = X + (size_t)(mBase + row4[i]) * 512 + seg4[i] * 8;
        areg[i][0] = *(const floatx4*)pa;
        areg[i][1] = *(const floatx4*)(pa + 4);
        breg[i] = *(const half8*)(BT + (size_t)(nBase + row4[i]) * 512 + seg4[i] * 8);
    }

    for (int kb = 0; kb < 512; kb += 64) {
        for (int i = 0; i < 4; i++) {
            *(half8*)&Asm[row4[i]][seg4[i] * 8] = cvt8r(areg[i][0], areg[i][1]);
            *(half8*)&Bsm[row4[i]][seg4[i] * 8] = breg[i];
        }
        __syncthreads();
        if (kb + 64 < 512) {
            int kn = kb + 64;
            for (int i = 0; i < 4; i++) {
                const float* pa = X + (size_t)(mBase + row4[i]) * 512 + kn + seg4[i] * 8;
                areg[i][0] = *(const floatx4*)pa;
                areg[i][1] = *(const floatx4*)(pa + 4);
                breg[i] = *(const half8*)(BT + (size_t)(nBase + row4[i]) * 512 + kn + seg4[i] * 8);
            }
        }
        for (int kc = 0; kc < 2; kc++) {
            int ko_ = kc * 32 + quad * 8;
            half8 a0 = *(const half8*)&Asm[mrow][ko_];
            half8 a1 = *(const half8*)&Asm[64 + mrow][ko_];
            for (int nt = 0; nt < 8; nt++) {
                half8 b = *(const half8*)&Bsm[nt * 16 + lrow][ko_];
                acc[0][nt] = __builtin_amdgcn_mfma_f32_16x16x32_f16(a0, b, acc[0][nt], 0, 0, 0);
                acc[1][nt] = __builtin_amdgcn_mfma_f32_16x16x32_f16(a1, b, acc[1][nt], 0, 0, 0);
            }
        }
        __syncthreads();
    }

    for (int mh = 0; mh < 2; mh++) {
        if (z == 2) {
            for (int nt = 0; nt < 8; nt++) {
                int gc = nBase + nt * 16 + lrow;
                float bb = bias[gc];
                int h = gc >> 6, hd = gc & 63;
                int gr = mBase + mh * 64 + wave * 16 + quad * 4;
                int b_ = gr >> 11, s = gr & 2047;
                half4 hv;
                for (int r = 0; r < 4; r++) hv[r] = (_Float16)(acc[mh][nt][r] + bb);
                *(half4*)(vto + (((size_t)(b_ * 8 + h) * 64 + hd) * 2048 + s)) = hv;
            }
        } else {
            _Float16* out = (z == 0) ? qo : ko2;
            for (int nt = 0; nt < 8; nt++) {
                int gc = nBase + nt * 16 + lrow;
                float bb = bias[gc];
                int h = gc >> 6, hd = gc & 63;
                for (int r = 0; r < 4; r++) {
                    int gr = mBase + mh * 64 + wave * 16 + quad * 4 + r;
                    int b_ = gr >> 11, s = gr & 2047;
                    out[(((size_t)b_ * 8 + h) * 2048 + s) * 64 + hd] = (_Float16)(acc[mh][nt][r] + bb);
                }
            }
        }
    }
}

// ---------------- K3: flash attention v9 (r1 exact revert): BM=64, 2 waves x 32q ----------------
__global__ __launch_bounds__(128) void attn_kernel(
        const _Float16* __restrict__ qws, const _Float16* __restrict__ kws,
        const _Float16* __restrict__ vtws, const int* __restrict__ vlens,
        _Float16* __restrict__ aout) {
    int idx = blockIdx.x;
    int b = ((idx & 3) + (idx >> 8)) & 3;   // stride-256 resident sets span all 4 batches
    int h = (idx >> 2) & 7;
    int q0 = ((idx >> 5) & 31) * 64;
    int bh = b * 8 + h;
    int L = vlens[b];
    bool uni = (L == 0);
    int nkt = uni ? 32 : ((L + 63) >> 6);
    int nfull = uni ? 0 : (L >> 6);

    int tid = threadIdx.x;
    int wq = tid >> 6;                  // wave -> 32-row q sub-block
    int lane = tid & 63;
    int l31 = lane & 31, hi = lane >> 5;

    __shared__ __align__(16) _Float16 ksm[64 * 64];
    __shared__ __align__(16) _Float16 vtsm[64 * 64];
    char* ksmB = (char*)ksm;
    char* vsmB = (char*)vtsm;

    const _Float16* kbase = kws + (size_t)bh * 2048 * 64;
    const _Float16* vtbase = vtws + (size_t)bh * 64 * 2048;

    half8 qf[4];
    {
        const _Float16* qrow = qws + ((size_t)bh * 2048 + q0 + wq * 32 + l31) * 64;
#pragma unroll
        for (int kc = 0; kc < 4; kc++) {
            qf[kc] = *(const half8*)(qrow + kc * 16 + hi * 8);
            qf[kc] = qf[kc] * (_Float16)(0.125f * LOG2E);
        }
    }

    floatx16 oacc0, oacc1;
#pragma unroll
    for (int i = 0; i < 16; i++) { oacc0[i] = 0.f; oacc1[i] = 0.f; }
    float rs = 0.f;

    int seg = tid & 7;                  // 8-half segment within a 64-half row
    int trow = tid >> 3;                // 0..15
    int xr = (l31 & 15) << 3;           // read-side swizzle constant

    half8 kreg[4], vreg[4];
#pragma unroll
    for (int i = 0; i < 4; i++) {
        int row = i * 16 + trow;
        kreg[i] = *(const half8*)(kbase + row * 64 + seg * 8);
        vreg[i] = *(const half8*)(vtbase + (size_t)row * 2048 + seg * 8);
    }

    for (int kt = 0; kt < nkt; kt++) {
        // stage K [key][hd] and V^T [hd][key] with swizzled 8B writes
#pragma unroll
        for (int i = 0; i < 4; i++) {
            int row = i * 16 + trow;
            int wo = row * 128 + ((seg * 16) ^ ((row & 15) << 3));
            H8U kv, vv;
            kv.h = kreg[i]; vv.h = vreg[i];
            *(uint2v*)(ksmB + wo) = kv.u[0];
            *(uint2v*)(ksmB + (wo ^ 8)) = kv.u[1];
            *(uint2v*)(vsmB + wo) = vv.u[0];
            *(uint2v*)(vsmB + (wo ^ 8)) = vv.u[1];
        }
        __syncthreads();
        if (kt + 1 < nkt) {
            const _Float16* ktn = kbase + (size_t)(kt + 1) * 4096;
            const _Float16* vtn = vtbase + (kt + 1) * 64;
#pragma unroll
            for (int i = 0; i < 4; i++) {
                int row = i * 16 + trow;
                kreg[i] = *(const half8*)(ktn + row * 64 + seg * 8);
                vreg[i] = *(const half8*)(vtn + (size_t)row * 2048 + seg * 8);
            }
        }

#pragma unroll
        for (int t = 0; t < 2; t++) {
            // S^T = K * (Q*c)^T : C col = q (l31), C row r -> key t*32 + (r&3)+8*(r>>2)+4*hi
            floatx16 sacc;
#pragma unroll
            for (int i = 0; i < 16; i++) sacc[i] = 0.f;
            int rbase = (t * 32 + l31) * 128;
#pragma unroll
            for (int kc = 0; kc < 4; kc++) {
                int off = rbase + ((kc * 32 + hi * 16) ^ xr);
                H8U kf;
                kf.u[0] = *(const uint2v*)(ksmB + off);
                kf.u[1] = *(const uint2v*)(ksmB + (off ^ 8));
                sacc = __builtin_amdgcn_mfma_f32_32x32x16_f16(kf.h, qf[kc], sacc, 0, 0, 0);
            }

            float p[16];
            if (kt < nfull) {
#pragma unroll
                for (int r = 0; r < 16; r++) p[r] = exp2f(sacc[r]);
            } else {
                int kb0 = kt * 64 + t * 32 + 4 * hi;
#pragma unroll
                for (int r = 0; r < 16; r++) {
                    int key = kb0 + (r & 3) + 8 * (r >> 2);
                    p[r] = uni ? 1.0f : ((key < L) ? exp2f(sacc[r]) : 0.0f);
                }
            }
#pragma unroll
            for (int r = 0; r < 16; r++) rs += p[r];

            // PV: k-slot sigma = hi*8+j maps to key 16s + 4*hi + (j&3) + 8*(j>>2).
#pragma unroll
            for (int s2 = 0; s2 < 2; s2++) {
                int s = t * 2 + s2;
                H8U pa;
#pragma unroll
                for (int j = 0; j < 8; j++) pa.h[j] = (_Float16)p[s2 * 8 + j];
                int cb = (s * 32 + hi * 8) ^ xr;
                {
                    int off = l31 * 128 + cb;
                    H8U vf;
                    vf.u[0] = *(const uint2v*)(vsmB + off);
                    vf.u[1] = *(const uint2v*)(vsmB + (off ^ 16));
                    oacc0 = __builtin_amdgcn_mfma_f32_32x32x16_f16(pa.h, vf.h, oacc0, 0, 0, 0);
                }
                {
                    int off = (32 + l31) * 128 + cb;
                    H8U vf;
                    vf.u[0] = *(const uint2v*)(vsmB + off);
                    vf.u[1] = *(const uint2v*)(vsmB + (off ^ 16));
                    oacc1 = __builtin_amdgcn_mfma_f32_32x32x16_f16(pa.h, vf.h, oacc1, 0, 0, 0);
                }
            }
        }
        __syncthreads();
    }

    // rowsum[q=l31] = own half + other half
    float rstot = rs + __shfl_xor(rs, 32, 64);
    _Float16* outb = aout + ((size_t)b * 2048 + q0 + wq * 32) * 512 + h * 64;
#pragma unroll
    for (int r = 0; r < 16; r++) {
        int qi = (r & 3) + 8 * (r >> 2) + 4 * hi;
        float inv = 1.0f / __shfl(rstot, qi, 64);
        outb[(size_t)qi * 512 + l31] = (_Float16)(oacc0[r] * inv);
        outb[(size_t)qi * 512 + 32 + l31] = (_Float16)(oacc1[r] * inv);
    }
}

// ---------------- K4: output projection, 128x128 tiles (2 m-strips/wave) -> f32 ----------------
__global__ __launch_bounds__(256) void gemm_out_kernel(
        const _Float16* __restrict__ A, const _Float16* __restrict__ BT,
        const float* __restrict__ bias, float* __restrict__ out) {
    __shared__ __align__(16) _Float16 Asm[128][72];
    __shared__ __align__(16) _Float16 Bsm[128][72];

    int tid = threadIdx.x;
    int wave = tid >> 6, lane = tid & 63;
    int lrow = lane & 15, quad = lane >> 4;
    int mBase = blockIdx.x * 128, nBase = blockIdx.y * 128;
    int mrow = wave * 16 + lrow;

    const floatx4 fz = {0.f, 0.f, 0.f, 0.f};
    floatx4 acc[2][8];
    for (int mh = 0; mh < 2; mh++)
        for (int i = 0; i < 8; i++) acc[mh][i] = fz;

    int row4[4], seg4[4];
    for (int i = 0; i < 4; i++) { int f = i * 256 + tid; row4[i] = f >> 3; seg4[i] = f & 7; }

    half8 areg[4], breg[4];
    for (int i = 0; i < 4; i++) {
        areg[i] = *(const half8*)(A + (size_t)(mBase + row4[i]) * 512 + seg4[i] * 8);
        breg[i] = *(const half8*)(BT + (size_t)(nBase + row4[i]) * 512 + seg4[i] * 8);
    }

    for (int kb = 0; kb < 512; kb += 64) {
        for (int i = 0; i < 4; i++) {
            *(half8*)&Asm[row4[i]][seg4[i] * 8] = areg[i];
            *(half8*)&Bsm[row4[i]][seg4[i] * 8] = breg[i];
        }
        __syncthreads();
        if (kb + 64 < 512) {
            int kn = kb + 64;
            for (int i = 0; i < 4; i++) {
                areg[i] = *(const half8*)(A + (size_t)(mBase + row4[i]) * 512 + kn + seg4[i] * 8);
                breg[i] = *(const half8*)(BT + (size_t)(nBase + row4[i]) * 512 + kn + seg4[i] * 8);
            }
        }
        for (int kc = 0; kc < 2; kc++) {
            int ko_ = kc * 32 + quad * 8;
            half8 a0 = *(const half8*)&Asm[mrow][ko_];
            half8 a1 = *(const half8*)&Asm[64 + mrow][ko_];
            for (int nt = 0; nt < 8; nt++) {
                half8 b = *(const half8*)&Bsm[nt * 16 + lrow][ko_];
                acc[0][nt] = __builtin_amdgcn_mfma_f32_16x16x32_f16(a0, b, acc[0][nt], 0, 0, 0);
                acc[1][nt] = __builtin_amdgcn_mfma_f32_16x16x32_f16(a1, b, acc[1][nt], 0, 0, 0);
            }
        }
        __syncthreads();
    }

    for (int mh = 0; mh < 2; mh++) {
        for (int nt = 0; nt < 8; nt++) {
            int gc = nBase + nt * 16 + lrow;
            float bb = bias[gc];
            for (int r = 0; r < 4; r++) {
                int gr = mBase + mh * 64 + wave * 16 + quad * 4 + r;
                out[(size_t)gr * 512 + gc] = acc[mh][nt][r] + bb;
            }
        }
    }
}

extern "C" void kernel_launch(void* const* d_in, const int* in_sizes, int n_in,
                              void* d_out, int out_size, void* d_ws, size_t ws_size,
                              hipStream_t stream) {
    const float* Q  = (const float*)d_in[0];
    const float* K  = (const float*)d_in[1];
    const float* V  = (const float*)d_in[2];
    const int*   VL = (const int*)d_in[3];
    const float* Wq = (const float*)d_in[4];
    const float* bq = (const float*)d_in[5];
    const float* Wk = (const float*)d_in[6];
    const float* bk = (const float*)d_in[7];
    const float* Wv = (const float*)d_in[8];
    const float* bv = (const float*)d_in[9];
    const float* Wo = (const float*)d_in[10];
    const float* bo = (const float*)d_in[11];

    char* ws = (char*)d_ws;
    _Float16* WT   = (_Float16*)ws;                                  // 2 MiB
    _Float16* qws  = (_Float16*)(ws + (size_t)(2)  * 1024 * 1024);   // 8 MiB [bh][s][hd]
    _Float16* kws  = (_Float16*)(ws + (size_t)(10) * 1024 * 1024);   // 8 MiB [bh][s][hd]
    _Float16* aout = (_Float16*)(ws + (size_t)(18) * 1024 * 1024);   // 8 MiB [8192,512]
    _Float16* vtws = (_Float16*)(ws + (size_t)(26) * 1024 * 1024);   // 8 MiB [bh][hd][s]

    transpose_w_kernel<<<dim3(8, 8, 4), 256, 0, stream>>>(Wq, Wk, Wv, Wo, WT);
    gemm_qkv_kernel<<<dim3(64, 4, 3), 256, 0, stream>>>(Q, K, V, WT, bq, bk, bv, VL, qws, kws, vtws);
    attn_kernel<<<dim3(1024, 1, 1), 128, 0, stream>>>(qws, kws, vtws, VL, aout);
    gemm_out_kernel<<<dim3(64, 4, 1), 256, 0, stream>>>(aout, WT + (size_t)3 * 512 * 512, bo, (float*)d_out);
}

// Round 7
// 192.642 us; speedup vs baseline: 1.4470x; 1.0311x over previous
//
#include <hip/hip_runtime.h>
#include <hip/hip_bf16.h>

typedef _Float16 half8 __attribute__((ext_vector_type(8)));
typedef _Float16 half4 __attribute__((ext_vector_type(4)));
typedef _Float16 half2t __attribute__((ext_vector_type(2)));
typedef float floatx4 __attribute__((ext_vector_type(4)));
typedef float floatx16 __attribute__((ext_vector_type(16)));
typedef unsigned int uint2v __attribute__((ext_vector_type(2)));

#define LOG2E 1.44269504088896340736f

__device__ __forceinline__ half8 cvt8r(floatx4 a, floatx4 b) {
    half8 h;
    h[0] = (_Float16)a[0]; h[1] = (_Float16)a[1]; h[2] = (_Float16)a[2]; h[3] = (_Float16)a[3];
    h[4] = (_Float16)b[0]; h[5] = (_Float16)b[1]; h[6] = (_Float16)b[2]; h[7] = (_Float16)b[3];
    return h;
}

union H8U { half8 h; half2t v2[4]; uint2v u[2]; };

// ---------------- K1: transpose + convert W (f32 [512x512]) -> WT fp16 [n][k] ----------------
__global__ __launch_bounds__(256) void transpose_w_kernel(
        const float* __restrict__ Wq, const float* __restrict__ Wk,
        const float* __restrict__ Wv, const float* __restrict__ Wo,
        _Float16* __restrict__ out) {
    const float* W = (blockIdx.z == 0) ? Wq : (blockIdx.z == 1) ? Wk : (blockIdx.z == 2) ? Wv : Wo;
    _Float16* o = out + (size_t)blockIdx.z * 512 * 512;
    __shared__ __align__(16) _Float16 t[64][72];
    int r0 = blockIdx.x * 64, c0 = blockIdx.y * 64;
    int tid = threadIdx.x;
    for (int i = 0; i < 2; i++) {
        int f = i * 256 + tid;
        int row = f >> 3, seg = f & 7;
        const float* p = W + (size_t)(r0 + row) * 512 + c0 + seg * 8;
        *(half8*)&t[row][seg * 8] = cvt8r(*(const floatx4*)p, *(const floatx4*)(p + 4));
    }
    __syncthreads();
    for (int i = 0; i < 2; i++) {
        int f = i * 256 + tid;
        int crow = f >> 3, seg = f & 7;
        half8 hv;
        for (int j = 0; j < 8; j++) hv[j] = t[seg * 8 + j][crow];
        *(half8*)(o + (size_t)(c0 + crow) * 512 + r0 + seg * 8) = hv;
    }
}

// ---------------- K2: QKV projection GEMM, 64x128 tiles; dead K/V blocks skipped ----------------
__global__ __launch_bounds__(256) void gemm_qkv_kernel(
        const float* __restrict__ Xq, const float* __restrict__ Xk, const float* __restrict__ Xv,
        const _Float16* __restrict__ WTall,
        const float* __restrict__ bq, const float* __restrict__ bk, const float* __restrict__ bv,
        const int* __restrict__ vlens,
        _Float16* __restrict__ qo, _Float16* __restrict__ ko2, _Float16* __restrict__ vto) {
    int z = blockIdx.z;
    int mBase = blockIdx.x * 64, nBase = blockIdx.y * 128;

    if (z >= 1) {
        int b_ = mBase >> 11, s0 = mBase & 2047;
        int L = vlens[b_];
        if (s0 >= L && !(z == 2 && L == 0)) return;
    }

    const float* X = (z == 0) ? Xq : (z == 1) ? Xk : Xv;
    const _Float16* BT = WTall + (size_t)z * 512 * 512;
    const float* bias = (z == 0) ? bq : (z == 1) ? bk : bv;

    __shared__ __align__(16) _Float16 Asm[64][72];
    __shared__ __align__(16) _Float16 Bsm[128][72];

    int tid = threadIdx.x;
    int wave = tid >> 6, lane = tid & 63;
    int lrow = lane & 15, quad = lane >> 4;
    int mrow = wave * 16 + lrow;

    const floatx4 fz = {0.f, 0.f, 0.f, 0.f};
    floatx4 acc[8];
    for (int i = 0; i < 8; i++) acc[i] = fz;

    int arow[2], aseg[2], brow[4], bseg[4];
    for (int i = 0; i < 2; i++) { int f = i * 256 + tid; arow[i] = f >> 3; aseg[i] = f & 7; }
    for (int i = 0; i < 4; i++) { int f = i * 256 + tid; brow[i] = f >> 3; bseg[i] = f & 7; }

    floatx4 areg[2][2];
    half8 breg[4];
    for (int i = 0; i < 2; i++) {
        const float* pa = X + (size_t)(mBase + arow[i]) * 512 + aseg[i] * 8;
        areg[i][0] = *(const floatx4*)pa;
        areg[i][1] = *(const floatx4*)(pa + 4);
    }
    for (int i = 0; i < 4; i++)
        breg[i] = *(const half8*)(BT + (size_t)(nBase + brow[i]) * 512 + bseg[i] * 8);

    for (int kb = 0; kb < 512; kb += 64) {
        for (int i = 0; i < 2; i++) *(half8*)&Asm[arow[i]][aseg[i] * 8] = cvt8r(areg[i][0], areg[i][1]);
        for (int i = 0; i < 4; i++) *(half8*)&Bsm[brow[i]][bseg[i] * 8] = breg[i];
        __syncthreads();
        if (kb + 64 < 512) {
            int kn = kb + 64;
            for (int i = 0; i < 2; i++) {
                const float* pa = X + (size_t)(mBase + arow[i]) * 512 + kn + aseg[i] * 8;
                areg[i][0] = *(const floatx4*)pa;
                areg[i][1] = *(const floatx4*)(pa + 4);
            }
            for (int i = 0; i < 4; i++)
                breg[i] = *(const half8*)(BT + (size_t)(nBase + brow[i]) * 512 + kn + bseg[i] * 8);
        }
        for (int kc = 0; kc < 2; kc++) {
            int ko_ = kc * 32 + quad * 8;
            half8 a = *(const half8*)&Asm[mrow][ko_];
            for (int nt = 0; nt < 8; nt++) {
                half8 b = *(const half8*)&Bsm[nt * 16 + lrow][ko_];
                acc[nt] = __builtin_amdgcn_mfma_f32_16x16x32_f16(a, b, acc[nt], 0, 0, 0);
            }
        }
        __syncthreads();
    }

    if (z == 2) {
        for (int nt = 0; nt < 8; nt++) {
            int gc = nBase + nt * 16 + lrow;
            float bb = bias[gc];
            int h = gc >> 6, hd = gc & 63;
            int gr = mBase + wave * 16 + quad * 4;
            int b_ = gr >> 11, s = gr & 2047;
            half4 hv;
            for (int r = 0; r < 4; r++) hv[r] = (_Float16)(acc[nt][r] + bb);
            *(half4*)(vto + (((size_t)(b_ * 8 + h) * 64 + hd) * 2048 + s)) = hv;
        }
    } else {
        _Float16* out = (z == 0) ? qo : ko2;
        for (int nt = 0; nt < 8; nt++) {
            int gc = nBase + nt * 16 + lrow;
            float bb = bias[gc];
            int h = gc >> 6, hd = gc & 63;
            for (int r = 0; r < 4; r++) {
                int gr = mBase + wave * 16 + quad * 4 + r;
                int b_ = gr >> 11, s = gr & 2047;
                out[(((size_t)b_ * 8 + h) * 2048 + s) * 64 + hd] = (_Float16)(acc[nt][r] + bb);
            }
        }
    }
}

// ---------------- K3: flash attention v16: BM=64, 4 waves (2 q-pairs x 2 key-splits) ----------------
// Wave (wq, ks) computes q-rows [q0+wq*32, +32) over tiles kt ≡ ks (mod 2) into additive partials
// (no running max -> exact). Double-buffered LDS; half-block tt stages buf[tt]; one barrier pair
// per 2 tiles. 16 waves/CU (4/SIMD) vs prior 1.08/SIMD -> latency chains hidden by TLP.
// End: ks=1 partials (oc, rs) combined into ks=0 via LDS scratch (reuses tile buffers).
__global__ __launch_bounds__(256) void attn_kernel(
        const _Float16* __restrict__ qws, const _Float16* __restrict__ kws,
        const _Float16* __restrict__ vtws, const int* __restrict__ vlens,
        _Float16* __restrict__ aout) {
    int idx = blockIdx.x;
    int b = ((idx & 3) + (idx >> 8)) & 3;   // stride-256 resident sets span all 4 batches
    int h = (idx >> 2) & 7;
    int q0 = ((idx >> 5) & 31) * 64;
    int bh = b * 8 + h;
    int L = vlens[b];
    bool uni = (L == 0);
    int nkt = uni ? 32 : ((L + 63) >> 6);
    int nfull = uni ? 0 : (L >> 6);

    int tid = threadIdx.x;
    int wid = tid >> 6;
    int wq = wid & 1, ks = wid >> 1;
    int lane = tid & 63;
    int l31 = lane & 31, hi = lane >> 5;

    __shared__ __align__(16) _Float16 ksm[2][64 * 64];   // 16 KiB (2 tile buffers)
    __shared__ __align__(16) _Float16 vtsm[2][64 * 64];  // 16 KiB

    const _Float16* kbase = kws + (size_t)bh * 2048 * 64;
    const _Float16* vtbase = vtws + (size_t)bh * 64 * 2048;

    half8 qf[4];
    {
        const _Float16* qrow = qws + ((size_t)bh * 2048 + q0 + wq * 32 + l31) * 64;
#pragma unroll
        for (int kc = 0; kc < 4; kc++) {
            qf[kc] = *(const half8*)(qrow + kc * 16 + hi * 8);
            qf[kc] = qf[kc] * (_Float16)(0.125f * LOG2E);
        }
    }

    floatx16 oacc0, oacc1;
#pragma unroll
    for (int i = 0; i < 16; i++) { oacc0[i] = 0.f; oacc1[i] = 0.f; }
    float rs = 0.f;

    // staging: half-block tt stages tile kt2+tt into buf[tt]; compute wave reads buf[ks] (tt==ks)
    int htid = tid & 127;
    int tt = tid >> 7;                  // == ks for every thread
    int seg = htid & 7;                 // 8-half segment
    int trow = htid >> 3;               // 0..15
    int xr = (l31 & 15) << 3;           // read-side swizzle constant
    char* ksmB = (char*)&ksm[tt][0];
    char* vsmB = (char*)&vtsm[tt][0];

    half8 kreg[4], vreg[4];
    if (tt < nkt) {
        const _Float16* kp = kbase + (size_t)tt * 4096;
        const _Float16* vp = vtbase + tt * 64;
#pragma unroll
        for (int i = 0; i < 4; i++) {
            int row = i * 16 + trow;
            kreg[i] = *(const half8*)(kp + row * 64 + seg * 8);
            vreg[i] = *(const half8*)(vp + (size_t)row * 2048 + seg * 8);
        }
    }

    for (int kt2 = 0; kt2 < nkt; kt2 += 2) {
        if (kt2 + tt < nkt) {
#pragma unroll
            for (int i = 0; i < 4; i++) {
                int row = i * 16 + trow;
                int wo = row * 128 + ((seg * 16) ^ ((row & 15) << 3));
                H8U kv, vv;
                kv.h = kreg[i]; vv.h = vreg[i];
                *(uint2v*)(ksmB + wo) = kv.u[0];
                *(uint2v*)(ksmB + (wo ^ 8)) = kv.u[1];
                *(uint2v*)(vsmB + wo) = vv.u[0];
                *(uint2v*)(vsmB + (wo ^ 8)) = vv.u[1];
            }
        }
        __syncthreads();
        int nxt = kt2 + 2 + tt;
        if (nxt < nkt) {
            const _Float16* kp = kbase + (size_t)nxt * 4096;
            const _Float16* vp = vtbase + nxt * 64;
#pragma unroll
            for (int i = 0; i < 4; i++) {
                int row = i * 16 + trow;
                kreg[i] = *(const half8*)(kp + row * 64 + seg * 8);
                vreg[i] = *(const half8*)(vp + (size_t)row * 2048 + seg * 8);
            }
        }

        int kt = kt2 + ks;
        if (kt < nkt) {
#pragma unroll
            for (int t = 0; t < 2; t++) {
                // S^T = K*(Q*c)^T : col = q (l31), row r -> key kt*64 + t*32 + (r&3)+8*(r>>2)+4*hi
                floatx16 sacc;
#pragma unroll
                for (int i = 0; i < 16; i++) sacc[i] = 0.f;
                int rbase = (t * 32 + l31) * 128;
#pragma unroll
                for (int kc = 0; kc < 4; kc++) {
                    int off = rbase + ((kc * 32 + hi * 16) ^ xr);
                    H8U kf;
                    kf.u[0] = *(const uint2v*)(ksmB + off);
                    kf.u[1] = *(const uint2v*)(ksmB + (off ^ 8));
                    sacc = __builtin_amdgcn_mfma_f32_32x32x16_f16(kf.h, qf[kc], sacc, 0, 0, 0);
                }

                float p[16];
                if (kt < nfull) {
#pragma unroll
                    for (int r = 0; r < 16; r++) p[r] = exp2f(sacc[r]);
                } else {
                    int kb0 = kt * 64 + t * 32 + 4 * hi;
#pragma unroll
                    for (int r = 0; r < 16; r++) {
                        int key = kb0 + (r & 3) + 8 * (r >> 2);
                        p[r] = uni ? 1.0f : ((key < L) ? exp2f(sacc[r]) : 0.0f);
                    }
                }
#pragma unroll
                for (int r = 0; r < 16; r++) rs += p[r];

                // PV: k-slot sigma = hi*8+j -> key 16s + 4*hi + (j&3) + 8*(j>>2)
#pragma unroll
                for (int s2 = 0; s2 < 2; s2++) {
                    int s = t * 2 + s2;
                    H8U pa;
#pragma unroll
                    for (int j = 0; j < 8; j++) pa.h[j] = (_Float16)p[s2 * 8 + j];
                    int cb = (s * 32 + hi * 8) ^ xr;
                    {
                        int off = l31 * 128 + cb;
                        H8U vf;
                        vf.u[0] = *(const uint2v*)(vsmB + off);
                        vf.u[1] = *(const uint2v*)(vsmB + (off ^ 16));
                        oacc0 = __builtin_amdgcn_mfma_f32_32x32x16_f16(pa.h, vf.h, oacc0, 0, 0, 0);
                    }
                    {
                        int off = (32 + l31) * 128 + cb;
                        H8U vf;
                        vf.u[0] = *(const uint2v*)(vsmB + off);
                        vf.u[1] = *(const uint2v*)(vsmB + (off ^ 16));
                        oacc1 = __builtin_amdgcn_mfma_f32_32x32x16_f16(pa.h, vf.h, oacc1, 0, 0, 0);
                    }
                }
            }
        }
        __syncthreads();
    }

    // ---- combine key-split partials: ks=1 -> LDS -> ks=0 adds ----
    float* ocs = (float*)&ksm[0][0];     // 4096 floats: [wq][32][64]
    float* rss = (float*)&vtsm[0][0];    // 128 floats:  [wq][64]
    if (ks == 1) {
        int sb = wq * 2048;
        rss[wq * 64 + lane] = rs;
#pragma unroll
        for (int i = 0; i < 16; i++) ocs[sb + i * 64 + lane] = oacc0[i];
#pragma unroll
        for (int i = 0; i < 16; i++) ocs[sb + (16 + i) * 64 + lane] = oacc1[i];
    }
    __syncthreads();
    if (ks == 0) {
        int sb = wq * 2048;
        rs += rss[wq * 64 + lane];
#pragma unroll
        for (int i = 0; i < 16; i++) oacc0[i] += ocs[sb + i * 64 + lane];
#pragma unroll
        for (int i = 0; i < 16; i++) oacc1[i] += ocs[sb + (16 + i) * 64 + lane];

        float rstot = rs + __shfl_xor(rs, 32, 64);
        _Float16* outb = aout + ((size_t)b * 2048 + q0 + wq * 32) * 512 + h * 64;
#pragma unroll
        for (int r = 0; r < 16; r++) {
            int qi = (r & 3) + 8 * (r >> 2) + 4 * hi;
            float inv = 1.0f / __shfl(rstot, qi, 64);
            outb[(size_t)qi * 512 + l31] = (_Float16)(oacc0[r] * inv);
            outb[(size_t)qi * 512 + 32 + l31] = (_Float16)(oacc1[r] * inv);
        }
    }
}

// ---------------- K4: output projection, 64x128 tiles (reg-prefetch dbuf) -> f32 ----------------
__global__ __launch_bounds__(256) void gemm_out_kernel(
        const _Float16* __restrict__ A, const _Float16* __restrict__ BT,
        const float* __restrict__ bias, float* __restrict__ out) {
    __shared__ __align__(16) _Float16 Asm[64][72];
    __shared__ __align__(16) _Float16 Bsm[128][72];

    int tid = threadIdx.x;
    int wave = tid >> 6, lane = tid & 63;
    int lrow = lane & 15, quad = lane >> 4;
    int mBase = blockIdx.x * 64, nBase = blockIdx.y * 128;
    int mrow = wave * 16 + lrow;

    const floatx4 fz = {0.f, 0.f, 0.f, 0.f};
    floatx4 acc[8];
    for (int i = 0; i < 8; i++) acc[i] = fz;

    int arow[2], aseg[2], brow[4], bseg[4];
    for (int i = 0; i < 2; i++) { int f = i * 256 + tid; arow[i] = f >> 3; aseg[i] = f & 7; }
    for (int i = 0; i < 4; i++) { int f = i * 256 + tid; brow[i] = f >> 3; bseg[i] = f & 7; }

    half8 areg[2], breg[4];
    for (int i = 0; i < 2; i++)
        areg[i] = *(const half8*)(A + (size_t)(mBase + arow[i]) * 512 + aseg[i] * 8);
    for (int i = 0; i < 4; i++)
        breg[i] = *(const half8*)(BT + (size_t)(nBase + brow[i]) * 512 + bseg[i] * 8);

    for (int kb = 0; kb < 512; kb += 64) {
        for (int i = 0; i < 2; i++) *(half8*)&Asm[arow[i]][aseg[i] * 8] = areg[i];
        for (int i = 0; i < 4; i++) *(half8*)&Bsm[brow[i]][bseg[i] * 8] = breg[i];
        __syncthreads();
        if (kb + 64 < 512) {
            int kn = kb + 64;
            for (int i = 0; i < 2; i++)
                areg[i] = *(const half8*)(A + (size_t)(mBase + arow[i]) * 512 + kn + aseg[i] * 8);
            for (int i = 0; i < 4; i++)
                breg[i] = *(const half8*)(BT + (size_t)(nBase + brow[i]) * 512 + kn + bseg[i] * 8);
        }
        for (int kc = 0; kc < 2; kc++) {
            int ko_ = kc * 32 + quad * 8;
            half8 a = *(const half8*)&Asm[mrow][ko_];
            for (int nt = 0; nt < 8; nt++) {
                half8 b = *(const half8*)&Bsm[nt * 16 + lrow][ko_];
                acc[nt] = __builtin_amdgcn_mfma_f32_16x16x32_f16(a, b, acc[nt], 0, 0, 0);
            }
        }
        __syncthreads();
    }

    for (int nt = 0; nt < 8; nt++) {
        int gc = nBase + nt * 16 + lrow;
        float bb = bias[gc];
        for (int r = 0; r < 4; r++) {
            int gr = mBase + wave * 16 + quad * 4 + r;
            out[(size_t)gr * 512 + gc] = acc[nt][r] + bb;
        }
    }
}

extern "C" void kernel_launch(void* const* d_in, const int* in_sizes, int n_in,
                              void* d_out, int out_size, void* d_ws, size_t ws_size,
                              hipStream_t stream) {
    const float* Q  = (const float*)d_in[0];
    const float* K  = (const float*)d_in[1];
    const float* V  = (const float*)d_in[2];
    const int*   VL = (const int*)d_in[3];
    const float* Wq = (const float*)d_in[4];
    const float* bq = (const float*)d_in[5];
    const float* Wk = (const float*)d_in[6];
    const float* bk = (const float*)d_in[7];
    const float* Wv = (const float*)d_in[8];
    const float* bv = (const float*)d_in[9];
    const float* Wo = (const float*)d_in[10];
    const float* bo = (const float*)d_in[11];

    char* ws = (char*)d_ws;
    _Float16* WT   = (_Float16*)ws;                                  // 2 MiB
    _Float16* qws  = (_Float16*)(ws + (size_t)(2)  * 1024 * 1024);   // 8 MiB [bh][s][hd]
    _Float16* kws  = (_Float16*)(ws + (size_t)(10) * 1024 * 1024);   // 8 MiB [bh][s][hd]
    _Float16* aout = (_Float16*)(ws + (size_t)(18) * 1024 * 1024);   // 8 MiB [8192,512]
    _Float16* vtws = (_Float16*)(ws + (size_t)(26) * 1024 * 1024);   // 8 MiB [bh][hd][s]

    transpose_w_kernel<<<dim3(8, 8, 4), 256, 0, stream>>>(Wq, Wk, Wv, Wo, WT);
    gemm_qkv_kernel<<<dim3(128, 4, 3), 256, 0, stream>>>(Q, K, V, WT, bq, bk, bv, VL, qws, kws, vtws);
    attn_kernel<<<dim3(1024, 1, 1), 256, 0, stream>>>(qws, kws, vtws, VL, aout);
    gemm_out_kernel<<<dim3(128, 4, 1), 256, 0, stream>>>(aout, WT + (size_t)3 * 512 * 512, bo, (float*)d_out);
}